// Round 1
// baseline (165.764 us; speedup 1.0000x reference)
//
#include <hip/hip_runtime.h>
#include <hip/hip_fp16.h>
#include <math.h>

#define NN 100000
#define NE 1600000
#define DIM 64
#define HST 72   // proj LDS stride in halves (144B, 16B-aligned rows)
#define PROJ_BLOCKS ((2 * NN) / 64)          // 3125
#define ROWPTR_BLOCKS ((NE + 255) / 256)     // 6250

typedef __attribute__((ext_vector_type(8))) __fp16 half8;
typedef __attribute__((ext_vector_type(4))) float f32x4;

__device__ __forceinline__ __half2 u2h2(unsigned u) { __half2 h; __builtin_memcpy(&h, &u, 4); return h; }
__device__ __forceinline__ unsigned h22u(__half2 h) { unsigned u; __builtin_memcpy(&u, &h, 4); return u; }
__device__ __forceinline__ unsigned pk_f16(float a, float b) {
    auto h = __builtin_amdgcn_cvt_pkrtz(a, b);   // one v_cvt_pkrtz_f16_f32
    unsigned u; __builtin_memcpy(&u, &h, 4); return u;
}

// ---------------------------------------------------------------------------
// Kernel 1 (fused): blocks [0,PROJ_BLOCKS) do the MFMA projection
// p = h @ W^T (f16, f32-acc) + a = p.w_attn; blocks [PROJ_BLOCKS, +ROWPTR_BLOCKS)
// do the CSR row_ptr boundary scan.
// NOTE (R10 post-mortem): non-temporal hints on h/src/out REGRESSED. Keep
// all accesses default-cached.
// ---------------------------------------------------------------------------
__global__ __launch_bounds__(256) void proj_kernel(
    const float* __restrict__ h_src, const float* __restrict__ h_dst,
    const float* __restrict__ W, const float* __restrict__ w_attn,
    const int* __restrict__ dst, int* __restrict__ row_ptr,
    unsigned* __restrict__ p16, float* __restrict__ a_src, float* __restrict__ a_dst) {
    __shared__ __align__(16) unsigned short Hh[64 * HST];  // f16 bits
    __shared__ __align__(16) unsigned short Wh[64 * HST];
    __shared__ float was[DIM];

    const int t = threadIdx.x;

    if (blockIdx.x >= PROJ_BLOCKS) {
        // ---- rowptr part: boundary scan over sorted dst ----
        int i = (blockIdx.x - PROJ_BLOCKS) * 256 + t;
        if (i >= NE) return;
        int d = dst[i];
        int prev = (i == 0) ? -1 : dst[i - 1];
        for (int n = prev + 1; n <= d; ++n) row_ptr[n] = i;
        if (i == NE - 1) {
            for (int n = d + 1; n <= NN; ++n) row_ptr[n] = NE;
        }
        return;
    }

    const int row0 = blockIdx.x * 64;

    // Stage W (f32 -> f16), coalesced float4 reads, contiguous 8B LDS writes.
#pragma unroll
    for (int r = 0; r < 4; ++r) {
        int idx = (r * 256 + t) * 4;           // flat float index into 64x64 W
        int j = idx >> 6, k = idx & 63;
        float4 v = *(const float4*)(W + idx);
        uint2 pk; pk.x = pk_f16(v.x, v.y); pk.y = pk_f16(v.z, v.w);
        *(uint2*)((char*)Wh + j * (HST * 2) + k * 2) = pk;
    }
    if (t < DIM) was[t] = w_attn[t];

    // Stage H tile (row-major, no transpose).
#pragma unroll
    for (int r = 0; r < 4; ++r) {
        int idx = (r * 256 + t) * 4;
        int row = idx >> 6, k = idx & 63;
        int grow = row0 + row;
        const float* hp = (grow < NN) ? h_src + (size_t)grow * DIM
                                      : h_dst + (size_t)(grow - NN) * DIM;
        float4 v = *(const float4*)(hp + k);
        uint2 pk; pk.x = pk_f16(v.x, v.y); pk.y = pk_f16(v.z, v.w);
        *(uint2*)((char*)Hh + row * (HST * 2) + k * 2) = pk;
    }
    __syncthreads();

    const int wv = t >> 6, lane = t & 63;
    const int col = lane & 15, quad = lane >> 4;
    const int m0 = wv * 16;

    const char* Hb = (const char*)Hh + (m0 + col) * (HST * 2) + quad * 16;
    half8 af0 = *(const half8*)(Hb);           // k = quad*8+j, k0=0
    half8 af1 = *(const half8*)(Hb + 64);      // k0=32

    f32x4 c[4];
#pragma unroll
    for (int n = 0; n < 4; ++n) {
        const char* Bb = (const char*)Wh + (n * 16 + col) * (HST * 2) + quad * 16;
        half8 b0 = *(const half8*)(Bb);
        half8 b1 = *(const half8*)(Bb + 64);
        f32x4 acc = {0.f, 0.f, 0.f, 0.f};
        acc = __builtin_amdgcn_mfma_f32_16x16x32_f16(af0, b0, acc, 0, 0, 0);
        acc = __builtin_amdgcn_mfma_f32_16x16x32_f16(af1, b1, acc, 0, 0, 0);
        c[n] = acc;
    }

    // a = p . w_attn : per-lane partial over its 4 cols, reduce 16 cols in group.
    float wv4[4];
#pragma unroll
    for (int n = 0; n < 4; ++n) wv4[n] = was[n * 16 + col];
#pragma unroll
    for (int reg = 0; reg < 4; ++reg) {
        float pa = c[0][reg] * wv4[0] + c[1][reg] * wv4[1] +
                   c[2][reg] * wv4[2] + c[3][reg] * wv4[3];
#pragma unroll
        for (int off = 1; off <= 8; off <<= 1) pa += __shfl_xor(pa, off);
        if (col == 0) {
            int grow = row0 + m0 + quad * 4 + reg;
            if (grow < NN) a_src[grow] = pa;
            else a_dst[grow - NN] = pa;
        }
    }

    // Pack p to f16 dwords via LDS repack, then fully-coalesced dwordx4 store.
    __syncthreads();
    unsigned* Pd = (unsigned*)Hh;              // reuse: 64 rows x 32 dwords
#pragma unroll
    for (int n = 0; n < 4; ++n) {
#pragma unroll
        for (int reg = 0; reg < 4; ++reg) {
            float other = __shfl_xor(c[n][reg], 1);
            if (!(col & 1)) {
                unsigned pk = pk_f16(c[n][reg], other);
                Pd[(m0 + quad * 4 + reg) * 32 + (n * 16 + col) / 2] = pk;
            }
        }
    }
    __syncthreads();
#pragma unroll
    for (int r = 0; r < 2; ++r) {
        int idx = (r * 256 + t) * 4;           // dword index into 2048-dword tile
        uint4 v = *(const uint4*)(Pd + idx);
        *(uint4*)(p16 + (size_t)row0 * 32 + idx) = v;
    }
}

// ---------------------------------------------------------------------------
// Kernel 2 (NEW): edge-parallel score pass. Computes, per edge,
//   w_e = exp(tanh(a_dst[dst_e] - a_src[src_e]))
// and stores a ready-to-consume 8B record ew[e] = {pk_f16(w,w), src*128}.
// Fully coalesced int4 reads of src/dst; a_* gathers are 4B over 400KB
// (L2-resident) and latency-hidden by edge-level TLP — this removes the
// a-gather + tanh/exp + LDS-bounce from agg's per-node critical chain.
// ---------------------------------------------------------------------------
__global__ __launch_bounds__(256) void edge_kernel(
    const int* __restrict__ src, const int* __restrict__ dst,
    const float* __restrict__ a_src, const float* __restrict__ a_dst,
    uint2* __restrict__ ew) {
    const int e0 = (blockIdx.x * 256 + threadIdx.x) * 4;
    if (e0 >= NE) return;
    int4 sv = *(const int4*)(src + e0);
    int4 dv = *(const int4*)(dst + e0);
    const int s[4] = {sv.x, sv.y, sv.z, sv.w};
    const int d[4] = {dv.x, dv.y, dv.z, dv.w};
    uint2 r[4];
#pragma unroll
    for (int j = 0; j < 4; ++j) {
        float x = a_dst[d[j]] - a_src[s[j]];
        float th = 1.f - 2.f / (__expf(2.f * x) + 1.f);   // tanh
        float w = __expf(th);                              // in [e^-1, e]
        r[j].x = pk_f16(w, w);
        r[j].y = (unsigned)s[j] * 128u;                    // pre-scaled byte offset
    }
    uint4* o = (uint4*)(ew + e0);
    o[0] = make_uint4(r[0].x, r[0].y, r[1].x, r[1].y);
    o[1] = make_uint4(r[2].x, r[2].y, r[3].x, r[3].y);
}

// ---------------------------------------------------------------------------
// Kernel 3: segment aggregation + ELU. Quarter-wave per node (16 lanes/node).
// Per-chunk chain is now just: ew load (L1/L2 broadcast) -> p16 gather.
// No LDS, no exp, no a-gather. Uniform path: always 8 records/lane; records
// past `end` are {w=0, off=0} — they gather the L1-hot row 0 and contribute
// exactly 0, so every node keeps the full 8-deep gather MLP, no divergence.
// h_diff[n] = p_dst[n] - (sum_e w_e * p_src[src_e]) / s   (sum alpha = 1)
// ---------------------------------------------------------------------------
__global__ __launch_bounds__(256) void agg_kernel(
    const char* __restrict__ p16base,    // rows of 128B f16; [0,NN)=src, [NN,2NN)=dst
    const uint2* __restrict__ ew,
    const int* __restrict__ row_ptr,
    float4* __restrict__ out4) {
    const int wv = threadIdx.x >> 6;
    const int lane = threadIdx.x & 63;
    const int g = lane >> 4;            // group (node) within wave
    const int glane = lane & 15;        // lane within group
    const int sub16 = glane >> 3;       // which edge of a pair
    const int chunk = glane & 7;        // which 16B chunk of the 128B row

    const int wid = (blockIdx.x * 4 + wv) * 4 + g;
    if (wid >= NN) return;

    const int beg = row_ptr[wid];
    const int end = row_ptr[wid + 1];

    if (end <= beg) {
        if (sub16 == 0) {
            const size_t ob = (size_t)wid * 16 + chunk * 2;
            out4[ob]     = make_float4(0.f, 0.f, 0.f, 0.f);
            out4[ob + 1] = make_float4(0.f, 0.f, 0.f, 0.f);
        }
        return;
    }

    // prefetch p_dst row chunk early (overlaps the edge loop)
    const uint4 pdu = *(const uint4*)(p16base + ((size_t)(NN + wid)) * 128 + (size_t)chunk * 16);

    const char* pbase = p16base + (size_t)chunk * 16;

    float sAcc = 0.f;
    __half2 acc[4];
#pragma unroll
    for (int q = 0; q < 4; ++q) acc[q] = u2h2(0u);

    for (int cb = beg; cb < end; cb += 16) {
        // 8 independent record loads (8 chunk-lanes share each address -> bcast)
        uint2 e[8];
#pragma unroll
        for (int q = 0; q < 8; ++q) {
            int idx = cb + 2 * q + sub16;
            uint2 v = make_uint2(0u, 0u);
            if (idx < end) v = ew[idx];
            e[q] = v;
        }
        // 8 independent dwordx4 gathers in flight
        uint4 r[8];
#pragma unroll
        for (int q = 0; q < 8; ++q) r[q] = *(const uint4*)(pbase + e[q].y);
#pragma unroll
        for (int q = 0; q < 8; ++q) {
            __half2 wq = u2h2(e[q].x);
            __half wl; __builtin_memcpy(&wl, &e[q].x, 2);
            sAcc += __half2float(wl);
            acc[0] = __hfma2(wq, u2h2(r[q].x), acc[0]);
            acc[1] = __hfma2(wq, u2h2(r[q].y), acc[1]);
            acc[2] = __hfma2(wq, u2h2(r[q].z), acc[2]);
            acc[3] = __hfma2(wq, u2h2(r[q].w), acc[3]);
        }
    }

    // every chunk-lane already holds its sub16-half's full sum: reduce sub16 only
    sAcc += __shfl_xor(sAcc, 8);
#pragma unroll
    for (int q = 0; q < 4; ++q)
        acc[q] = __hadd2(acc[q], u2h2(__shfl_xor(h22u(acc[q]), 8)));

    if (sub16 == 0) {   // 8 lanes per group write the node's 64 channels
        const unsigned pw[4] = {pdu.x, pdu.y, pdu.z, pdu.w};
        const float inv = 1.f / sAcc;
        float o[8];
#pragma unroll
        for (int q = 0; q < 4; ++q) {
            float2 pf = __half22float2(u2h2(pw[q]));
            float2 af = __half22float2(acc[q]);
            float h0 = pf.x - af.x * inv;
            float h1 = pf.y - af.y * inv;
            o[2 * q]     = h0 > 0.f ? h0 : __expf(h0) - 1.f;
            o[2 * q + 1] = h1 > 0.f ? h1 : __expf(h1) - 1.f;
        }
        const size_t ob = (size_t)wid * 16 + chunk * 2;
        out4[ob]     = make_float4(o[0], o[1], o[2], o[3]);
        out4[ob + 1] = make_float4(o[4], o[5], o[6], o[7]);
    }
}

// ---------------------------------------------------------------------------
extern "C" void kernel_launch(void* const* d_in, const int* in_sizes, int n_in,
                              void* d_out, int out_size, void* d_ws, size_t ws_size,
                              hipStream_t stream) {
    const float* h_src = (const float*)d_in[0];
    const float* h_dst = (const float*)d_in[1];
    const float* W     = (const float*)d_in[2];
    const float* w_at  = (const float*)d_in[3];
    const int*   src   = (const int*)d_in[4];
    const int*   dst   = (const int*)d_in[5];

    char* ws = (char*)d_ws;
    unsigned* p16 = (unsigned*)ws;                        // 2NN*32 dwords = 25.6 MB
    float* a_src = (float*)(ws + (size_t)2 * NN * 32 * 4);
    float* a_dst = a_src + NN;
    int* row_ptr = (int*)(a_dst + NN);                    // NN+1 ints
    // ew after row_ptr, 16B-aligned
    size_t ew_off = (size_t)2 * NN * 32 * 4 + (size_t)2 * NN * 4 + (size_t)(NN + 1) * 4;
    ew_off = (ew_off + 15) & ~(size_t)15;
    uint2* ew = (uint2*)(ws + ew_off);                    // NE*8 = 12.8 MB

    hipLaunchKernelGGL(proj_kernel, dim3(PROJ_BLOCKS + ROWPTR_BLOCKS), dim3(256), 0, stream,
                       h_src, h_dst, W, w_at, dst, row_ptr, p16, a_src, a_dst);
    hipLaunchKernelGGL(edge_kernel, dim3((NE / 4 + 255) / 256), dim3(256), 0, stream,
                       src, dst, a_src, a_dst, ew);
    hipLaunchKernelGGL(agg_kernel, dim3((NN + 15) / 16), dim3(256), 0, stream,
                       (const char*)p16, ew, row_ptr, (float4*)d_out);
}

// Round 2
// 146.808 us; speedup vs baseline: 1.1291x; 1.1291x over previous
//
#include <hip/hip_runtime.h>
#include <hip/hip_fp16.h>
#include <math.h>

#define NN 100000
#define NE 1600000
#define DIM 64
#define HST 72   // proj LDS stride in halves (144B, 16B-aligned rows)
#define PROJ_BLOCKS ((2 * NN) / 64)          // 3125
#define ROWPTR_BLOCKS ((NE + 255) / 256)     // 6250

typedef __attribute__((ext_vector_type(8))) __fp16 half8;
typedef __attribute__((ext_vector_type(4))) float f32x4;

__device__ __forceinline__ __half2 u2h2(unsigned u) { __half2 h; __builtin_memcpy(&h, &u, 4); return h; }
__device__ __forceinline__ unsigned h22u(__half2 h) { unsigned u; __builtin_memcpy(&u, &h, 4); return u; }
__device__ __forceinline__ unsigned pk_f16(float a, float b) {
    auto h = __builtin_amdgcn_cvt_pkrtz(a, b);   // one v_cvt_pkrtz_f16_f32
    unsigned u; __builtin_memcpy(&u, &h, 4); return u;
}
__device__ __forceinline__ float f16lo(unsigned u) {
    __half h; __builtin_memcpy(&h, &u, 2); return __half2float(h);
}

// ---------------------------------------------------------------------------
// Kernel 1 (fused): blocks [0,PROJ_BLOCKS) do the MFMA projection
// p = h @ W^T (f16, f32-acc) + a = p.w_attn; blocks [PROJ_BLOCKS, +ROWPTR_BLOCKS)
// do the CSR row_ptr boundary scan.
// NOTE (R10 post-mortem): non-temporal hints on h/src/out REGRESSED. Keep
// all accesses default-cached.
// NOTE (R1' post-mortem): splitting the edge-score into its own kernel was
// pure overhead (+15us) — agg is gather-service-bound, not score-chain-bound.
// ---------------------------------------------------------------------------
__global__ __launch_bounds__(256) void proj_kernel(
    const float* __restrict__ h_src, const float* __restrict__ h_dst,
    const float* __restrict__ W, const float* __restrict__ w_attn,
    const int* __restrict__ dst, int* __restrict__ row_ptr,
    unsigned* __restrict__ p16, float* __restrict__ a_src, float* __restrict__ a_dst) {
    __shared__ __align__(16) unsigned short Hh[64 * HST];  // f16 bits
    __shared__ __align__(16) unsigned short Wh[64 * HST];
    __shared__ float was[DIM];

    const int t = threadIdx.x;

    if (blockIdx.x >= PROJ_BLOCKS) {
        // ---- rowptr part: boundary scan over sorted dst ----
        int i = (blockIdx.x - PROJ_BLOCKS) * 256 + t;
        if (i >= NE) return;
        int d = dst[i];
        int prev = (i == 0) ? -1 : dst[i - 1];
        for (int n = prev + 1; n <= d; ++n) row_ptr[n] = i;
        if (i == NE - 1) {
            for (int n = d + 1; n <= NN; ++n) row_ptr[n] = NE;
        }
        return;
    }

    const int row0 = blockIdx.x * 64;

    // Stage W (f32 -> f16), coalesced float4 reads, contiguous 8B LDS writes.
#pragma unroll
    for (int r = 0; r < 4; ++r) {
        int idx = (r * 256 + t) * 4;           // flat float index into 64x64 W
        int j = idx >> 6, k = idx & 63;
        float4 v = *(const float4*)(W + idx);
        uint2 pk; pk.x = pk_f16(v.x, v.y); pk.y = pk_f16(v.z, v.w);
        *(uint2*)((char*)Wh + j * (HST * 2) + k * 2) = pk;
    }
    if (t < DIM) was[t] = w_attn[t];

    // Stage H tile (row-major, no transpose).
#pragma unroll
    for (int r = 0; r < 4; ++r) {
        int idx = (r * 256 + t) * 4;
        int row = idx >> 6, k = idx & 63;
        int grow = row0 + row;
        const float* hp = (grow < NN) ? h_src + (size_t)grow * DIM
                                      : h_dst + (size_t)(grow - NN) * DIM;
        float4 v = *(const float4*)(hp + k);
        uint2 pk; pk.x = pk_f16(v.x, v.y); pk.y = pk_f16(v.z, v.w);
        *(uint2*)((char*)Hh + row * (HST * 2) + k * 2) = pk;
    }
    __syncthreads();

    const int wv = t >> 6, lane = t & 63;
    const int col = lane & 15, quad = lane >> 4;
    const int m0 = wv * 16;

    const char* Hb = (const char*)Hh + (m0 + col) * (HST * 2) + quad * 16;
    half8 af0 = *(const half8*)(Hb);           // k = quad*8+j, k0=0
    half8 af1 = *(const half8*)(Hb + 64);      // k0=32

    f32x4 c[4];
#pragma unroll
    for (int n = 0; n < 4; ++n) {
        const char* Bb = (const char*)Wh + (n * 16 + col) * (HST * 2) + quad * 16;
        half8 b0 = *(const half8*)(Bb);
        half8 b1 = *(const half8*)(Bb + 64);
        f32x4 acc = {0.f, 0.f, 0.f, 0.f};
        acc = __builtin_amdgcn_mfma_f32_16x16x32_f16(af0, b0, acc, 0, 0, 0);
        acc = __builtin_amdgcn_mfma_f32_16x16x32_f16(af1, b1, acc, 0, 0, 0);
        c[n] = acc;
    }

    // a = p . w_attn : per-lane partial over its 4 cols, reduce 16 cols in group.
    float wv4[4];
#pragma unroll
    for (int n = 0; n < 4; ++n) wv4[n] = was[n * 16 + col];
#pragma unroll
    for (int reg = 0; reg < 4; ++reg) {
        float pa = c[0][reg] * wv4[0] + c[1][reg] * wv4[1] +
                   c[2][reg] * wv4[2] + c[3][reg] * wv4[3];
#pragma unroll
        for (int off = 1; off <= 8; off <<= 1) pa += __shfl_xor(pa, off);
        if (col == 0) {
            int grow = row0 + m0 + quad * 4 + reg;
            if (grow < NN) a_src[grow] = pa;
            else a_dst[grow - NN] = pa;
        }
    }

    // Pack p to f16 dwords via LDS repack, then fully-coalesced dwordx4 store.
    __syncthreads();
    unsigned* Pd = (unsigned*)Hh;              // reuse: 64 rows x 32 dwords
#pragma unroll
    for (int n = 0; n < 4; ++n) {
#pragma unroll
        for (int reg = 0; reg < 4; ++reg) {
            float other = __shfl_xor(c[n][reg], 1);
            if (!(col & 1)) {
                unsigned pk = pk_f16(c[n][reg], other);
                Pd[(m0 + quad * 4 + reg) * 32 + (n * 16 + col) / 2] = pk;
            }
        }
    }
    __syncthreads();
#pragma unroll
    for (int r = 0; r < 2; ++r) {
        int idx = (r * 256 + t) * 4;           // dword index into 2048-dword tile
        uint4 v = *(const uint4*)(Pd + idx);
        *(uint4*)(p16 + (size_t)row0 * 32 + idx) = v;
    }
}

// ---------------------------------------------------------------------------
// Kernel 2: fused edge-score + segment softmax + aggregation + ELU.
// Quarter-wave per node (16 lanes/node, 4 nodes/wave, 16/block).
// UNIFIED edge loop (R2): one code path, always 8 records/lane from the
// wave-private LDS buffer (zero-filled beyond cd) and 8 independent dwordx4
// gathers in flight. Dummy records {w=0, off=0} gather the L1-hot row 0 and
// contribute exactly 0 — removes the divergent 2-deep slow path that nearly
// every node's final partial chunk used to take (both paths ran serially
// whenever the 4 groups of a wave disagreed, i.e. almost always).
// h_diff[n] = p_dst[n] - (sum_e w_e * p_src[src_e]) / s   (sum alpha = 1)
// ---------------------------------------------------------------------------
__global__ __launch_bounds__(256) void agg_kernel(
    const char* __restrict__ p16base,    // rows of 128B f16; [0,NN)=src, [NN,2NN)=dst
    const float* __restrict__ a_src, const float* __restrict__ a_dst,
    const int* __restrict__ src, const int* __restrict__ row_ptr,
    float4* __restrict__ out4) {
    __shared__ uint2 buf[4][64];
    const int wv = threadIdx.x >> 6;
    const int lane = threadIdx.x & 63;
    const int g = lane >> 4;            // group (node) within wave
    const int glane = lane & 15;        // lane within group
    const int sub16 = glane >> 3;       // which edge of a pair
    const int chunk = glane & 7;        // which 16B chunk of the 128B row

    const int wid = (blockIdx.x * 4 + wv) * 4 + g;
    if (wid >= NN) return;

    const int beg = row_ptr[wid];
    const int end = row_ptr[wid + 1];

    if (end <= beg) {
        if (sub16 == 0) {
            const size_t ob = (size_t)wid * 16 + chunk * 2;
            out4[ob]     = make_float4(0.f, 0.f, 0.f, 0.f);
            out4[ob + 1] = make_float4(0.f, 0.f, 0.f, 0.f);
        }
        return;
    }

    // prefetch p_dst row chunk early (overlaps the edge loop)
    const uint4 pdu = *(const uint4*)(p16base + ((size_t)(NN + wid)) * 128 + (size_t)chunk * 16);

    const float ad = a_dst[wid];
    const char* pbase = p16base + (size_t)chunk * 16;
    uint2* bufw = buf[wv];
    const int gbase = g * 16;

    float sAcc = 0.f;
    __half2 acc[4];
#pragma unroll
    for (int q = 0; q < 4; ++q) acc[q] = u2h2(0u);

    for (int cb = beg; cb < end; cb += 16) {
        int cd = end - cb; if (cd > 16) cd = 16;
        uint2 pk = make_uint2(0u, 0u);
        if (glane < cd) {
            int sv = src[cb + glane];                  // ~coalesced
            float x = ad - a_src[sv];                  // 4B gather, L2-resident
            float th = 1.f - 2.f / (__expf(2.f * x) + 1.f);   // tanh
            float w = __expf(th);
            pk.x = pk_f16(w, w);
            pk.y = (unsigned)sv * 128u;                // pre-scaled byte offset
        }
        bufw[lane] = pk;                               // wave-private, no barrier

        // unified 8-deep path: 8 record reads then 8 gathers in flight
        uint2 e[8];
#pragma unroll
        for (int q = 0; q < 8; ++q) e[q] = bufw[gbase + 2 * q + sub16];
        uint4 r[8];
#pragma unroll
        for (int q = 0; q < 8; ++q) r[q] = *(const uint4*)(pbase + e[q].y);
#pragma unroll
        for (int q = 0; q < 8; ++q) {
            __half2 wq = u2h2(e[q].x);
            sAcc += f16lo(e[q].x);
            acc[0] = __hfma2(wq, u2h2(r[q].x), acc[0]);
            acc[1] = __hfma2(wq, u2h2(r[q].y), acc[1]);
            acc[2] = __hfma2(wq, u2h2(r[q].z), acc[2]);
            acc[3] = __hfma2(wq, u2h2(r[q].w), acc[3]);
        }
    }

    // lanes within a sub16-half hold identical sums: reduce across sub16 only
    sAcc += __shfl_xor(sAcc, 8);
#pragma unroll
    for (int q = 0; q < 4; ++q)
        acc[q] = __hadd2(acc[q], u2h2(__shfl_xor(h22u(acc[q]), 8)));

    if (sub16 == 0) {   // 8 lanes per group write the node's 64 channels
        const unsigned pw[4] = {pdu.x, pdu.y, pdu.z, pdu.w};
        const float inv = 1.f / sAcc;
        float o[8];
#pragma unroll
        for (int q = 0; q < 4; ++q) {
            float2 pf = __half22float2(u2h2(pw[q]));
            float2 af = __half22float2(acc[q]);
            float h0 = pf.x - af.x * inv;
            float h1 = pf.y - af.y * inv;
            o[2 * q]     = h0 > 0.f ? h0 : __expf(h0) - 1.f;
            o[2 * q + 1] = h1 > 0.f ? h1 : __expf(h1) - 1.f;
        }
        const size_t ob = (size_t)wid * 16 + chunk * 2;
        out4[ob]     = make_float4(o[0], o[1], o[2], o[3]);
        out4[ob + 1] = make_float4(o[4], o[5], o[6], o[7]);
    }
}

// ---------------------------------------------------------------------------
extern "C" void kernel_launch(void* const* d_in, const int* in_sizes, int n_in,
                              void* d_out, int out_size, void* d_ws, size_t ws_size,
                              hipStream_t stream) {
    const float* h_src = (const float*)d_in[0];
    const float* h_dst = (const float*)d_in[1];
    const float* W     = (const float*)d_in[2];
    const float* w_at  = (const float*)d_in[3];
    const int*   src   = (const int*)d_in[4];
    const int*   dst   = (const int*)d_in[5];

    char* ws = (char*)d_ws;
    unsigned* p16 = (unsigned*)ws;                        // 2NN*32 dwords = 25.6 MB
    float* a_src = (float*)(ws + (size_t)2 * NN * 32 * 4);
    float* a_dst = a_src + NN;
    int* row_ptr = (int*)(a_dst + NN);                    // NN+1

    hipLaunchKernelGGL(proj_kernel, dim3(PROJ_BLOCKS + ROWPTR_BLOCKS), dim3(256), 0, stream,
                       h_src, h_dst, W, w_at, dst, row_ptr, p16, a_src, a_dst);
    hipLaunchKernelGGL(agg_kernel, dim3((NN + 15) / 16), dim3(256), 0, stream,
                       (const char*)p16, a_src, a_dst, src, row_ptr,
                       (float4*)d_out);
}